// Round 1
// baseline (419.085 us; speedup 1.0000x reference)
//
#include <hip/hip_runtime.h>

// SpikeLoss: loss = 0.5 * sum((outputs - psp(target))^2)
// psp: syn_t = syn_{t-1}*0.8 + x_t, emit syn_t/5   (tau=5)
// Shape [B=16, C=128, H=16, W=16, T=100], T contiguous. 524288 neurons.
//
// R6: R5 was latency/duty-cycle bound (132us/dispatch vs 66us roofline,
// VALUBusy 7.5%, HBM 20%): loads only in flight during Phase A; zero bytes
// in flight during compute + block teardown + relaunch -> ~50% memory duty.
// This version: persistent-ish blocks, each processing 8 chunks of 32
// neurons with DOUBLE-BUFFERED LDS and COUNTED vmcnt waits (T3+T4 pattern):
// chunk k+1's DMA is in flight while chunk k computes. All in-loop barriers
// are raw s_barrier + targeted asm waitcnt (NEVER __syncthreads, which
// drains vmcnt(0) and kills the pipeline).
// DMA is wave-uniform: 100 B/thread/array = 6x16B + 1x4B -> exactly 14 VMEM
// instructions per wave per chunk -> s_waitcnt vmcnt(14) == "previous chunk
// landed". LDS 2x25.6KB buffers -> 3 blocks/CU, ~150KB/CU in flight
// continuously.
// Reduction structure reproduces R5's partials bit-exactly: per-64-neuron
// group g, partial[g] = ((w0+w1)+w2)+w3 with identical per-lane fma chains
// and identical shfl trees (old block g == chunks 2g,2g+1 here).

#define T_STEPS 100
#define SEG 25
#define NPC 32                                // neurons per chunk
#define BLOCK 128
#define CPB 8                                 // chunks per block
#define CHUNK_FLOATS (NPC * T_STEPS)          // 3200 floats = 12.8 KB
#define N_NEURONS (16 * 128 * 16 * 16)        // 524288
#define TOTAL_CHUNKS (N_NEURONS / NPC)        // 16384
#define GRID_P (TOTAL_CHUNKS / CPB)           // 2048 blocks
#define NPARTS (N_NEURONS / 64)               // 8192 64-neuron groups (== R5)

#define GLOBAL_AS __attribute__((address_space(1)))
#define LDS_AS __attribute__((address_space(3)))

__device__ __forceinline__ void async_f4(const float4* g, float4* l) {
  // DMA 16 B/lane global->LDS. LDS dest is wave-uniform base + lane*16;
  // per-lane pointers that already include lane*16 match that (contiguous t).
  __builtin_amdgcn_global_load_lds((const GLOBAL_AS void*)g, (LDS_AS void*)l,
                                   16, 0, 0);
}
__device__ __forceinline__ void async_f1(const float* g, float* l) {
  __builtin_amdgcn_global_load_lds((const GLOBAL_AS void*)g, (LDS_AS void*)l,
                                   4, 0, 0);
}

// Issue one chunk's staging: 3200 floats x 2 arrays over 128 threads.
// Per thread: 6x16B + 1x4B per array = 100 B. Per WAVE: exactly 14 VMEM
// instructions (uniform across waves -> counted vmcnt is exact).
__device__ __forceinline__ void issue_chunk(const float* gx, const float* go,
                                            float* lx, float* lo, int tid) {
  const float4* gx4 = reinterpret_cast<const float4*>(gx);
  const float4* go4 = reinterpret_cast<const float4*>(go);
  float4* lx4 = reinterpret_cast<float4*>(lx);
  float4* lo4 = reinterpret_cast<float4*>(lo);
#pragma unroll
  for (int it = 0; it < 6; ++it)
    async_f4(gx4 + it * BLOCK + tid, lx4 + it * BLOCK + tid);
  async_f1(gx + 6 * BLOCK * 4 + tid, lx + 6 * BLOCK * 4 + tid);  // floats 3072..3199
#pragma unroll
  for (int it = 0; it < 6; ++it)
    async_f4(go4 + it * BLOCK + tid, lo4 + it * BLOCK + tid);
  async_f1(go + 6 * BLOCK * 4 + tid, lo + 6 * BLOCK * 4 + tid);
}

template <bool WRITE_PARTIAL>
__device__ __forceinline__ void block_body(const float* __restrict__ outputs,
                                           const float* __restrict__ target,
                                           float* __restrict__ partial,
                                           float* __restrict__ out) {
  __shared__ float xbuf[2][CHUNK_FLOATS];  // 2 x 12.8 KB
  __shared__ float obuf[2][CHUNK_FLOATS];  // 2 x 12.8 KB
  __shared__ float lE[BLOCK];              // segment-end syn
  __shared__ float ws2[2][2];              // [chunk parity][wave] sums

  const int tid = threadIdx.x;
  const size_t base = (size_t)blockIdx.x * (CPB * CHUNK_FLOATS);
  const float* tg = target + base;
  const float* og = outputs + base;

  // Prologue: fill buffer 0 (14 VMEM/wave outstanding).
  issue_chunk(tg, og, xbuf[0], obuf[0], tid);

  const int n = tid >> 2;  // neuron within chunk (0..31)
  const int s = tid & 3;   // segment (0..3)
  const float A25 = 3.77789319e-3f;  // 0.8^25
  const float A50 = 1.42724769e-5f;  // 0.8^50
  float bsum = 0.f;  // atomic-fallback accumulator (tid 0 only)

  for (int k = 0; k < CPB; ++k) {
    const int cur = k & 1;

    // ---- issue next chunk, then counted wait for current chunk ----
    if (k + 1 < CPB) {
      issue_chunk(tg + (size_t)(k + 1) * CHUNK_FLOATS,
                  og + (size_t)(k + 1) * CHUNK_FLOATS,
                  xbuf[cur ^ 1], obuf[cur ^ 1], tid);
      // 28 of our loads outstanding; leave next chunk's 14 in flight.
      asm volatile("s_waitcnt vmcnt(14)" ::: "memory");
    } else {
      asm volatile("s_waitcnt vmcnt(0)" ::: "memory");
    }
    __builtin_amdgcn_sched_barrier(0);
    __builtin_amdgcn_s_barrier();  // all waves' current-chunk DMA landed
    __builtin_amdgcn_sched_barrier(0);

    // addr = n*100 + s*25 + j = 25*tid + j -> stride 25 (odd): conflict-free.
    const float* xrow = &xbuf[cur][n * T_STEPS + s * SEG];
    const float* orow = &obuf[cur][n * T_STEPS + s * SEG];

    // ---- B1: per-thread segment scan ----
    float E = 0.f;
#pragma unroll
    for (int j = 0; j < SEG; ++j) E = fmaf(E, 0.8f, xrow[j]);
    lE[tid] = E;
    asm volatile("s_waitcnt lgkmcnt(0)" ::: "memory");
    __builtin_amdgcn_s_barrier();
    __builtin_amdgcn_sched_barrier(0);

    // carry = syn at end of previous segments (exact compose)
    float carry = 0.f;
    if (s >= 1) carry = lE[tid - 1];
    if (s >= 2) carry = fmaf(A25, lE[tid - 2], carry);
    if (s >= 3) carry = fmaf(A50, lE[tid - 3], carry);

    // ---- B2: rescan with carry seed; accumulate loss ----
    float syn = carry;
    float acc = 0.f;
#pragma unroll
    for (int j = 0; j < SEG; ++j) {
      syn = fmaf(syn, 0.8f, xrow[j]);
      float d = fmaf(-0.2f, syn, orow[j]);
      acc = fmaf(d, d, acc);
    }

    // ---- per-chunk wave reduction (same tree as R5) ----
#pragma unroll
    for (int off = 32; off > 0; off >>= 1) acc += __shfl_down(acc, off, 64);
    if ((tid & 63) == 0) ws2[cur][tid >> 6] = acc;

    // Trailing barrier: (a) ws2 visible, (b) all reads of buf[cur] done
    // before next iteration's DMA overwrites it.
    asm volatile("s_waitcnt lgkmcnt(0)" ::: "memory");
    __builtin_amdgcn_sched_barrier(0);
    __builtin_amdgcn_s_barrier();
    __builtin_amdgcn_sched_barrier(0);

    if (cur == 1 && tid == 0) {
      // 64-neuron group sum, association identical to R5's
      // wsum[0]+wsum[1]+wsum[2]+wsum[3].
      float g = ((ws2[0][0] + ws2[0][1]) + ws2[1][0]) + ws2[1][1];
      if (WRITE_PARTIAL) {
        partial[(size_t)blockIdx.x * (CPB / 2) + (k >> 1)] = g;
      } else {
        bsum += g;
      }
    }
  }

  if (!WRITE_PARTIAL && tid == 0) atomicAdd(out, 0.5f * bsum);
}

__global__ __launch_bounds__(BLOCK) void spike_loss_partial(
    const float* __restrict__ outputs,
    const float* __restrict__ target,
    float* __restrict__ partial) {
  block_body<true>(outputs, target, partial, nullptr);
}

// Deterministic final reduction over per-group partials; applies the 0.5.
// (Identical to R5: nparts = 8192, same order.)
__global__ __launch_bounds__(256) void spike_loss_final(
    const float* __restrict__ partial, float* __restrict__ out, int nparts) {
  float acc = 0.0f;
  for (int i = threadIdx.x; i < nparts; i += 256) acc += partial[i];
#pragma unroll
  for (int off = 32; off > 0; off >>= 1) acc += __shfl_down(acc, off, 64);
  __shared__ float wsum[4];
  const int lane = threadIdx.x & 63;
  const int wid = threadIdx.x >> 6;
  if (lane == 0) wsum[wid] = acc;
  __syncthreads();
  if (threadIdx.x == 0) out[0] = 0.5f * (wsum[0] + wsum[1] + wsum[2] + wsum[3]);
}

// Fallback if d_ws is unusably small: atomic finish into d_out.
__global__ __launch_bounds__(BLOCK) void spike_loss_atomic(
    const float* __restrict__ outputs,
    const float* __restrict__ target,
    float* __restrict__ out) {
  block_body<false>(outputs, target, nullptr, out);
}

extern "C" void kernel_launch(void* const* d_in, const int* in_sizes, int n_in,
                              void* d_out, int out_size, void* d_ws, size_t ws_size,
                              hipStream_t stream) {
  const float* outputs = (const float*)d_in[0];
  const float* target = (const float*)d_in[1];
  float* out = (float*)d_out;

  if (ws_size >= NPARTS * sizeof(float)) {
    float* partial = (float*)d_ws;
    spike_loss_partial<<<GRID_P, BLOCK, 0, stream>>>(outputs, target, partial);
    spike_loss_final<<<1, 256, 0, stream>>>(partial, out, NPARTS);
  } else {
    hipMemsetAsync(out, 0, sizeof(float), stream);
    spike_loss_atomic<<<GRID_P, BLOCK, 0, stream>>>(outputs, target, out);
  }
}

// Round 3
// 407.867 us; speedup vs baseline: 1.0275x; 1.0275x over previous
//
#include <hip/hip_runtime.h>

// SpikeLoss: loss = 0.5 * sum((outputs - psp(target))^2)
// psp: syn_t = syn_{t-1}*0.8 + x_t, emit syn_t/5   (tau=5)
// Shape [B=16, C=128, H=16, W=16, T=100], T contiguous. 524288 neurons.
//
// R8: R5/R6 both delivered ~3 TB/s (2x roofline) with different pipelining;
// shared limiter = 52 KB LDS -> 3 blocks/CU -> too few resident waves to
// keep memory busy across barrier/drain windows. R7 tried to halve LDS but
// had a 4x OOB in its compare phase (per-thread share is 6.25 float4, not
// 25) -> fault. R8 keeps the halved-LDS plan with R5's exact math:
//   - ONE 25.6 KB buffer, used sequentially: DMA target -> LDS; pull each
//     thread's 25-float row into registers; barrier; DMA outputs into the
//     SAME buffer (overlaps E-scan + carry compose); __syncthreads (drains
//     vmcnt); fused rescan+compare reads outputs row-wise from LDS.
//   - carry compose via 3 intra-wave __shfl_up (4-lane groups): no lE[],
//     two fewer barriers than R5.
//   - Per-element fma chains, compose order, reduce tree, and the
//     8192-partial layout are IDENTICAL to R5 (absmax 0.0 preserved).
// LDS = 25.7 KB -> 6 blocks/CU = 24 waves/CU (vs 3 blocks/12 waves in R5).
// __launch_bounds__(256,6) caps VGPR at 85; live set ~ xr[25]+20 -> no spill.

#define T_STEPS 100
#define SEG 25
#define NPB 64                           // neurons per block
#define BLOCK 256
#define N_NEURONS (16 * 128 * 16 * 16)   // 524288
#define GRID_P (N_NEURONS / NPB)         // 8192 blocks
#define NPARTS GRID_P                    // one partial per 64-neuron block
#define BLK_FLOATS (NPB * T_STEPS)       // 6400 floats = 25.6 KB

#define GLOBAL_AS __attribute__((address_space(1)))
#define LDS_AS __attribute__((address_space(3)))

__device__ __forceinline__ void async_f4(const float4* g, float4* l) {
  // DMA 16 B/lane global->LDS. LDS dest is wave-uniform base + lane*16;
  // per-lane pointers that already include tid*16 match that.
  __builtin_amdgcn_global_load_lds((const GLOBAL_AS void*)g, (LDS_AS void*)l,
                                   16, 0, 0);
}
__device__ __forceinline__ void async_f1(const float* g, float* l) {
  __builtin_amdgcn_global_load_lds((const GLOBAL_AS void*)g, (LDS_AS void*)l,
                                   4, 0, 0);
}

// Stage one 6400-float array: 6x16B + 1x4B per thread = 1536 float4 + 256
// floats = 6400 floats. Exactly 7 VMEM instructions per thread.
__device__ __forceinline__ void stage(const float* __restrict__ g,
                                      float* lds, int tid) {
  const float4* g4 = reinterpret_cast<const float4*>(g);
  float4* l4 = reinterpret_cast<float4*>(lds);
#pragma unroll
  for (int it = 0; it < 6; ++it)
    async_f4(g4 + it * BLOCK + tid, l4 + it * BLOCK + tid);
  async_f1(g + 6 * BLOCK * 4 + tid, lds + 6 * BLOCK * 4 + tid);
}

template <bool WRITE_PARTIAL>
__device__ __forceinline__ void block_body(const float* __restrict__ outputs,
                                           const float* __restrict__ target,
                                           float* __restrict__ partial,
                                           float* __restrict__ out) {
  __shared__ float buf[BLK_FLOATS];  // target, then reused for outputs
  __shared__ float wsum[BLOCK / 64];

  const int tid = threadIdx.x;
  const size_t base = (size_t)blockIdx.x * BLK_FLOATS;

  // ---- Phase A: DMA target into LDS ----
  stage(target + base, buf, tid);
  __syncthreads();  // drains vmcnt (DMA landed) + barrier

  // ---- Phase B: pull row into registers ----
  // thread tid owns floats [25*tid, 25*tid+25): neuron n = tid>>2, seg s = tid&3.
  // Bank for fixed j: (25*tid+j)%32, gcd(25,32)=1 -> 2-way across 64 lanes -> free.
  const int s = tid & 3;
  const int rowoff = tid * SEG;
  float xr[SEG];
#pragma unroll
  for (int j = 0; j < SEG; ++j) xr[j] = buf[rowoff + j];

  __syncthreads();  // ALL waves finished reading x before we overwrite buf

  // ---- Phase A2: DMA outputs into the same buffer (async; overlaps below) ----
  stage(outputs + base, buf, tid);

  // ---- E-scan + carry compose (identical chains to R5) ----
  float E = 0.f;
#pragma unroll
  for (int j = 0; j < SEG; ++j) E = fmaf(E, 0.8f, xr[j]);

  const float A25 = 3.77789319e-3f;  // 0.8^25
  const float A50 = 1.42724769e-5f;  // 0.8^50
  const float e1 = __shfl_up(E, 1, 4);
  const float e2 = __shfl_up(E, 2, 4);
  const float e3 = __shfl_up(E, 3, 4);
  float carry = 0.f;
  if (s >= 1) carry = e1;
  if (s >= 2) carry = fmaf(A25, e2, carry);
  if (s >= 3) carry = fmaf(A50, e3, carry);

  __syncthreads();  // drains vmcnt(0): outputs landed; barrier orders all waves

  // ---- Phase C: fused rescan + compare (x from regs, outputs from LDS) ----
  float syn = carry;
  float acc = 0.f;
#pragma unroll
  for (int j = 0; j < SEG; ++j) {
    syn = fmaf(syn, 0.8f, xr[j]);
    float d = fmaf(-0.2f, syn, buf[rowoff + j]);
    acc = fmaf(d, d, acc);
  }

  // ---- block reduction (same tree as R5) ----
#pragma unroll
  for (int off = 32; off > 0; off >>= 1) acc += __shfl_down(acc, off, 64);
  const int lane = tid & 63;
  const int wid = tid >> 6;
  if (lane == 0) wsum[wid] = acc;
  __syncthreads();
  const float blocksum = ((wsum[0] + wsum[1]) + wsum[2]) + wsum[3];

  if (tid == 0) {
    if (WRITE_PARTIAL) partial[blockIdx.x] = blocksum;
    else atomicAdd(out, 0.5f * blocksum);
  }
}

__global__ __launch_bounds__(BLOCK, 6) void spike_loss_partial(
    const float* __restrict__ outputs,
    const float* __restrict__ target,
    float* __restrict__ partial) {
  block_body<true>(outputs, target, partial, nullptr);
}

// Deterministic final reduction over per-block partials; applies the 0.5.
__global__ __launch_bounds__(256) void spike_loss_final(
    const float* __restrict__ partial, float* __restrict__ out, int nparts) {
  float acc = 0.0f;
  for (int i = threadIdx.x; i < nparts; i += 256) acc += partial[i];
#pragma unroll
  for (int off = 32; off > 0; off >>= 1) acc += __shfl_down(acc, off, 64);
  __shared__ float wsum[4];
  const int lane = threadIdx.x & 63;
  const int wid = threadIdx.x >> 6;
  if (lane == 0) wsum[wid] = acc;
  __syncthreads();
  if (threadIdx.x == 0) out[0] = 0.5f * (wsum[0] + wsum[1] + wsum[2] + wsum[3]);
}

// Fallback if d_ws is unusably small: atomic finish into d_out.
__global__ __launch_bounds__(BLOCK, 6) void spike_loss_atomic(
    const float* __restrict__ outputs,
    const float* __restrict__ target,
    float* __restrict__ out) {
  block_body<false>(outputs, target, nullptr, out);
}

extern "C" void kernel_launch(void* const* d_in, const int* in_sizes, int n_in,
                              void* d_out, int out_size, void* d_ws, size_t ws_size,
                              hipStream_t stream) {
  const float* outputs = (const float*)d_in[0];
  const float* target = (const float*)d_in[1];
  float* out = (float*)d_out;

  if (ws_size >= NPARTS * sizeof(float)) {
    float* partial = (float*)d_ws;
    spike_loss_partial<<<GRID_P, BLOCK, 0, stream>>>(outputs, target, partial);
    spike_loss_final<<<1, 256, 0, stream>>>(partial, out, NPARTS);
  } else {
    hipMemsetAsync(out, 0, sizeof(float), stream);
    spike_loss_atomic<<<GRID_P, BLOCK, 0, stream>>>(outputs, target, out);
  }
}